// Round 6
// baseline (618.862 us; speedup 1.0000x reference)
//
#include <hip/hip_runtime.h>

#define N_GRID 144
#define INV_DX 128.0f
#define NBINS 32768          // 32 x 32 x 32 bins of 4^3 cells
#define SCAN_THREADS 1024
#define PER_THREAD 32        // 1024 * 32 = 32768
#define KP 8                 // particles per thread in streaming passes

__device__ __forceinline__ int bin_of(float px, float py, float pz) {
    int bx = (int)(px * INV_DX);   // 0..127
    int by = (int)(py * INV_DX);
    int bz = (int)(pz * INV_DX);
    return ((bx >> 2) << 10) | ((by >> 2) << 5) | (bz >> 2);
}

__global__ void __launch_bounds__(256) hist_kernel(
    const float* __restrict__ pos, unsigned int* __restrict__ hist, int n)
{
    int base = blockIdx.x * (blockDim.x * KP) + threadIdx.x;
    float px[KP], py[KP], pz[KP];
    int ok[KP];
#pragma unroll
    for (int k = 0; k < KP; ++k) {
        int p = base + k * 256;
        ok[k] = (p < n);
        int q = ok[k] ? p : 0;
        px[k] = pos[3 * q + 0];
        py[k] = pos[3 * q + 1];
        pz[k] = pos[3 * q + 2];
    }
#pragma unroll
    for (int k = 0; k < KP; ++k) {
        if (ok[k]) atomicAdd(&hist[bin_of(px[k], py[k], pz[k])], 1u);
    }
}

__global__ void __launch_bounds__(SCAN_THREADS) scan_kernel(
    const unsigned int* __restrict__ hist, unsigned int* __restrict__ offs)
{
    __shared__ unsigned int partial[SCAN_THREADS];
    int t = threadIdx.x;
    unsigned int local[PER_THREAD];
    unsigned int s = 0;
    int base = t * PER_THREAD;
#pragma unroll
    for (int k = 0; k < PER_THREAD; ++k) {
        local[k] = s;
        s += hist[base + k];
    }
    partial[t] = s;
    __syncthreads();
    for (int d = 1; d < SCAN_THREADS; d <<= 1) {
        unsigned int v = (t >= d) ? partial[t - d] : 0u;
        __syncthreads();
        partial[t] += v;
        __syncthreads();
    }
    unsigned int chunk_excl = (t == 0) ? 0u : partial[t - 1];
#pragma unroll
    for (int k = 0; k < PER_THREAD; ++k)
        offs[base + k] = chunk_excl + local[k];
}

// Unfiltered: every particle claims its destination slot; rank[] written
// fully coalesced (full lines, all lanes active).
__global__ void __launch_bounds__(256) rank_kernel(
    const float* __restrict__ pos, unsigned int* __restrict__ offs,
    unsigned int* __restrict__ rank, int n)
{
    int base = blockIdx.x * (blockDim.x * KP) + threadIdx.x;
    float px[KP], py[KP], pz[KP];
    int ok[KP];
#pragma unroll
    for (int k = 0; k < KP; ++k) {
        int p = base + k * 256;
        ok[k] = (p < n);
        int q = ok[k] ? p : 0;
        px[k] = pos[3 * q + 0];
        py[k] = pos[3 * q + 1];
        pz[k] = pos[3 * q + 2];
    }
    unsigned int r[KP];
#pragma unroll
    for (int k = 0; k < KP; ++k) {
        if (ok[k]) r[k] = atomicAdd(&offs[bin_of(px[k], py[k], pz[k])], 1u);
    }
#pragma unroll
    for (int k = 0; k < KP; ++k) {
        int p = base + k * 256;
        if (ok[k]) rank[p] = r[k];
    }
}

// XCD-filtered store: 8 blocks per chunk; block (chunk, owner) stores only
// particles whose DESTINATION slot lies in octant `owner` of sorted[].
// All writers of any sorted cache line share an octant -> same XCD ->
// partial-line stores merge in that XCD's L2. No atomics here.
__global__ void __launch_bounds__(256) store_kernel(
    const float* __restrict__ pos, const unsigned int* __restrict__ rank,
    float4* __restrict__ sorted, int n, unsigned int n8)
{
    int owner = blockIdx.x & 7;
    int chunk = blockIdx.x >> 3;
    int base = chunk * (256 * KP) + threadIdx.x;
    unsigned int lo = owner * n8;
    unsigned int hi = lo + n8;
    unsigned int r[KP];
    int ok[KP];
#pragma unroll
    for (int k = 0; k < KP; ++k) {
        int p = base + k * 256;
        ok[k] = (p < n);
        r[k] = rank[ok[k] ? p : 0];
        ok[k] = ok[k] && (r[k] >= lo) && (r[k] < hi);
    }
#pragma unroll
    for (int k = 0; k < KP; ++k) {
        int p = base + k * 256;
        if (ok[k]) {
            float4 v;
            v.x = pos[3 * p + 0];
            v.y = pos[3 * p + 1];
            v.z = pos[3 * p + 2];
            v.w = 0.0f;
            sorted[r[k]] = v;
        }
    }
}

// Reads sorted[j] (coalesced), gathers grid (bin-local), writes result IN
// PLACE over sorted[j] (coalesced full-line float4 writes, no amplification).
__global__ void __launch_bounds__(256) gather_kernel(
    const float* __restrict__ grid,
    float4* __restrict__ sorted, int n)
{
    int j = blockIdx.x * blockDim.x + threadIdx.x;
    if (j >= n) return;

    float4 p = sorted[j];

    float nx = p.x * INV_DX;
    float ny = p.y * INV_DX;
    float nz = p.z * INV_DX;

    int bx = (int)nx;
    int by = (int)ny;
    int bz = (int)nz;

    float lx = nx - (float)bx;
    float ly = ny - (float)by;
    float lz = nz - (float)bz;

    float wx[3], wy[3], wz[3];
    wx[0] = 0.5f * (1.0f - lx) * (1.0f - lx);
    wx[1] = 0.75f - (0.5f - lx) * (0.5f - lx);
    wx[2] = 0.5f * lx * lx;
    wy[0] = 0.5f * (1.0f - ly) * (1.0f - ly);
    wy[1] = 0.75f - (0.5f - ly) * (0.5f - ly);
    wy[2] = 0.5f * ly * ly;
    wz[0] = 0.5f * (1.0f - lz) * (1.0f - lz);
    wz[1] = 0.75f - (0.5f - lz) * (0.5f - lz);
    wz[2] = 0.5f * lz * lz;

    const int s1 = N_GRID * 3;
    const int s0 = N_GRID * N_GRID * 3;
    const float* gbase = grid + (long)bx * s0 + by * s1 + bz * 3;

    float ox = 0.0f, oy = 0.0f, oz = 0.0f;

#pragma unroll
    for (int a = 0; a < 3; ++a) {
#pragma unroll
        for (int b = 0; b < 3; ++b) {
            const float* pp = gbase + a * s0 + b * s1;
            float wab = wx[a] * wy[b];
            float g0x = pp[0], g0y = pp[1], g0z = pp[2];
            float g1x = pp[3], g1y = pp[4], g1z = pp[5];
            float g2x = pp[6], g2y = pp[7], g2z = pp[8];
            float w0 = wab * wz[0];
            float w1 = wab * wz[1];
            float w2 = wab * wz[2];
            ox += w0 * g0x + w1 * g1x + w2 * g2x;
            oy += w0 * g0y + w1 * g1y + w2 * g2y;
            oz += w0 * g0z + w1 * g1z + w2 * g2z;
        }
    }

    float4 res;
    res.x = ox; res.y = oy; res.z = oz; res.w = 0.0f;
    sorted[j] = res;
}

// out[i] = res[rank[i]]: coalesced rank read, ONE random 64B line READ per
// particle (clean, no writeback), coalesced full-line out writes.
__global__ void __launch_bounds__(256) permute_kernel(
    const float4* __restrict__ res, const unsigned int* __restrict__ rank,
    float* __restrict__ out, int n)
{
    int base = blockIdx.x * (256 * KP) + threadIdx.x;
    unsigned int r[KP];
    int ok[KP];
#pragma unroll
    for (int k = 0; k < KP; ++k) {
        int p = base + k * 256;
        ok[k] = (p < n);
        r[k] = rank[ok[k] ? p : 0];
    }
    float4 v[KP];
#pragma unroll
    for (int k = 0; k < KP; ++k) {
        v[k] = res[r[k]];
    }
#pragma unroll
    for (int k = 0; k < KP; ++k) {
        int p = base + k * 256;
        if (ok[k]) {
            out[3 * p + 0] = v[k].x;
            out[3 * p + 1] = v[k].y;
            out[3 * p + 2] = v[k].z;
        }
    }
}

// ---------- Tier-2 fallback (R5 pipeline, 65 MB ws) ----------
__global__ void __launch_bounds__(256) scatter_kernel_t2(
    const float* __restrict__ pos, float4* __restrict__ sorted,
    unsigned int* __restrict__ offs, int n)
{
    int owner = blockIdx.x & 7;
    int chunk = blockIdx.x >> 3;
    int base = chunk * (256 * KP) + threadIdx.x;
    float px[KP], py[KP], pz[KP];
    int ok[KP], pidx[KP], bn[KP];
    unsigned int off[KP];
#pragma unroll
    for (int k = 0; k < KP; ++k) {
        int p = base + k * 256;
        ok[k] = (p < n);
        pidx[k] = p;
        int q = ok[k] ? p : 0;
        px[k] = pos[3 * q + 0];
        py[k] = pos[3 * q + 1];
        pz[k] = pos[3 * q + 2];
    }
#pragma unroll
    for (int k = 0; k < KP; ++k) {
        bn[k] = bin_of(px[k], py[k], pz[k]);
        ok[k] = ok[k] && ((bn[k] >> 12) == owner);
    }
#pragma unroll
    for (int k = 0; k < KP; ++k) {
        if (ok[k]) off[k] = atomicAdd(&offs[bn[k]], 1u);
    }
#pragma unroll
    for (int k = 0; k < KP; ++k) {
        if (ok[k]) {
            float4 v;
            v.x = px[k]; v.y = py[k]; v.z = pz[k]; v.w = __int_as_float(pidx[k]);
            sorted[off[k]] = v;
        }
    }
}

__global__ void __launch_bounds__(256) gather_kernel_t2(
    const float* __restrict__ grid,
    const float4* __restrict__ sorted,
    float* __restrict__ out, int n)
{
    int j = blockIdx.x * blockDim.x + threadIdx.x;
    if (j >= n) return;
    float4 p = sorted[j];
    int idx = __float_as_int(p.w);
    float nx = p.x * INV_DX, ny = p.y * INV_DX, nz = p.z * INV_DX;
    int bx = (int)nx, by = (int)ny, bz = (int)nz;
    float lx = nx - bx, ly = ny - by, lz = nz - bz;
    float wx[3], wy[3], wz[3];
    wx[0] = 0.5f * (1.0f - lx) * (1.0f - lx);
    wx[1] = 0.75f - (0.5f - lx) * (0.5f - lx);
    wx[2] = 0.5f * lx * lx;
    wy[0] = 0.5f * (1.0f - ly) * (1.0f - ly);
    wy[1] = 0.75f - (0.5f - ly) * (0.5f - ly);
    wy[2] = 0.5f * ly * ly;
    wz[0] = 0.5f * (1.0f - lz) * (1.0f - lz);
    wz[1] = 0.75f - (0.5f - lz) * (0.5f - lz);
    wz[2] = 0.5f * lz * lz;
    const int s1 = N_GRID * 3, s0 = N_GRID * N_GRID * 3;
    const float* gbase = grid + (long)bx * s0 + by * s1 + bz * 3;
    float ox = 0, oy = 0, oz = 0;
#pragma unroll
    for (int a = 0; a < 3; ++a)
#pragma unroll
        for (int b = 0; b < 3; ++b) {
            const float* pp = gbase + a * s0 + b * s1;
            float wab = wx[a] * wy[b];
            float w0 = wab * wz[0], w1 = wab * wz[1], w2 = wab * wz[2];
            ox += w0 * pp[0] + w1 * pp[3] + w2 * pp[6];
            oy += w0 * pp[1] + w1 * pp[4] + w2 * pp[7];
            oz += w0 * pp[2] + w1 * pp[5] + w2 * pp[8];
        }
    out[3 * idx + 0] = ox;
    out[3 * idx + 1] = oy;
    out[3 * idx + 2] = oz;
}

// Tier-3 fallback: naive
__global__ void __launch_bounds__(256) g2p_naive_kernel(
    const float* __restrict__ grid, const float* __restrict__ pos,
    float* __restrict__ out, int n)
{
    int i = blockIdx.x * blockDim.x + threadIdx.x;
    if (i >= n) return;
    float px = pos[3 * i + 0], py = pos[3 * i + 1], pz = pos[3 * i + 2];
    float nx = px * INV_DX, ny = py * INV_DX, nz = pz * INV_DX;
    int bx = (int)nx, by = (int)ny, bz = (int)nz;
    float lx = nx - bx, ly = ny - by, lz = nz - bz;
    float wx[3], wy[3], wz[3];
    wx[0] = 0.5f * (1.0f - lx) * (1.0f - lx);
    wx[1] = 0.75f - (0.5f - lx) * (0.5f - lx);
    wx[2] = 0.5f * lx * lx;
    wy[0] = 0.5f * (1.0f - ly) * (1.0f - ly);
    wy[1] = 0.75f - (0.5f - ly) * (0.5f - ly);
    wy[2] = 0.5f * ly * ly;
    wz[0] = 0.5f * (1.0f - lz) * (1.0f - lz);
    wz[1] = 0.75f - (0.5f - lz) * (0.5f - lz);
    wz[2] = 0.5f * lz * lz;
    const int s1 = N_GRID * 3, s0 = N_GRID * N_GRID * 3;
    const float* gbase = grid + (long)bx * s0 + by * s1 + bz * 3;
    float ox = 0, oy = 0, oz = 0;
#pragma unroll
    for (int a = 0; a < 3; ++a)
#pragma unroll
        for (int b = 0; b < 3; ++b) {
            const float* pp = gbase + a * s0 + b * s1;
            float wab = wx[a] * wy[b];
            float w0 = wab * wz[0], w1 = wab * wz[1], w2 = wab * wz[2];
            ox += w0 * pp[0] + w1 * pp[3] + w2 * pp[6];
            oy += w0 * pp[1] + w1 * pp[4] + w2 * pp[7];
            oz += w0 * pp[2] + w1 * pp[5] + w2 * pp[8];
        }
    out[3 * i + 0] = ox;
    out[3 * i + 1] = oy;
    out[3 * i + 2] = oz;
}

extern "C" void kernel_launch(void* const* d_in, const int* in_sizes, int n_in,
                              void* d_out, int out_size, void* d_ws, size_t ws_size,
                              hipStream_t stream) {
    const float* grid = (const float*)d_in[0];
    const float* pos  = (const float*)d_in[1];
    float* out        = (float*)d_out;
    int n = in_sizes[1] / 3;

    int block = 256;
    int blocks = (n + block - 1) / block;
    int blocksK = (n + block * KP - 1) / (block * KP);

    // ws layout: [0,128K) hist | [128K,256K) offs | [1M,1M+4n) rank | [1M+4n (16-aligned), +16n) sorted/res
    size_t rank_off = (1u << 20);
    size_t sorted_off = (rank_off + (size_t)n * 4 + 255) & ~(size_t)255;
    size_t need1 = sorted_off + (size_t)n * sizeof(float4);
    size_t need2 = (1u << 20) + (size_t)n * sizeof(float4);

    if (ws_size >= need1) {
        unsigned int* hist = (unsigned int*)d_ws;
        unsigned int* offs = hist + NBINS;
        unsigned int* rank = (unsigned int*)((char*)d_ws + rank_off);
        float4* sorted = (float4*)((char*)d_ws + sorted_off);
        unsigned int n8 = (unsigned int)((n + 7) / 8);

        hipMemsetAsync(hist, 0, NBINS * sizeof(unsigned int), stream);
        hist_kernel<<<blocksK, block, 0, stream>>>(pos, hist, n);
        scan_kernel<<<1, SCAN_THREADS, 0, stream>>>(hist, offs);
        rank_kernel<<<blocksK, block, 0, stream>>>(pos, offs, rank, n);
        store_kernel<<<blocksK * 8, block, 0, stream>>>(pos, rank, sorted, n, n8);
        gather_kernel<<<blocks, block, 0, stream>>>(grid, sorted, n);
        permute_kernel<<<blocksK, block, 0, stream>>>(sorted, rank, out, n);
    } else if (ws_size >= need2) {
        unsigned int* hist = (unsigned int*)d_ws;
        unsigned int* offs = hist + NBINS;
        float4* sorted = (float4*)((char*)d_ws + (1u << 20));

        hipMemsetAsync(hist, 0, NBINS * sizeof(unsigned int), stream);
        hist_kernel<<<blocksK, block, 0, stream>>>(pos, hist, n);
        scan_kernel<<<1, SCAN_THREADS, 0, stream>>>(hist, offs);
        scatter_kernel_t2<<<blocksK * 8, block, 0, stream>>>(pos, sorted, offs, n);
        gather_kernel_t2<<<blocks, block, 0, stream>>>(grid, sorted, out, n);
    } else {
        g2p_naive_kernel<<<blocks, block, 0, stream>>>(grid, pos, out, n);
    }
}

// Round 7
// 475.285 us; speedup vs baseline: 1.3021x; 1.3021x over previous
//
#include <hip/hip_runtime.h>

#define N_GRID 144
#define INV_DX 128.0f
#define NBINS 32768          // 32 x 32 x 32 bins of 4^3 cells
#define SCAN_THREADS 1024
#define PER_THREAD 32        // 1024 * 32 = 32768
#define KP 8                 // particles per thread in streaming passes

__device__ __forceinline__ int bin_of(float px, float py, float pz) {
    int bx = (int)(px * INV_DX);   // 0..127
    int by = (int)(py * INV_DX);
    int bz = (int)(pz * INV_DX);
    return ((bx >> 2) << 10) | ((by >> 2) << 5) | (bz >> 2);
}

// Pass 0: bin16[i] = bin index (coalesced read/write, no atomics)
__global__ void __launch_bounds__(256) binify_kernel(
    const float* __restrict__ pos, unsigned short* __restrict__ bin16, int n)
{
    int base = blockIdx.x * (blockDim.x * KP) + threadIdx.x;
#pragma unroll
    for (int k = 0; k < KP; ++k) {
        int p = base + k * 256;
        if (p < n) {
            float px = pos[3 * p + 0];
            float py = pos[3 * p + 1];
            float pz = pos[3 * p + 2];
            bin16[p] = (unsigned short)bin_of(px, py, pz);
        }
    }
}

// Pass 1: octant-filtered histogram. Block (chunk, owner) counts only bins in
// x-octant `owner` (bin>>12 == owner). With round-robin blockIdx->XCD mapping
// each XCD's atomics hit a private 16KB hist slice -> L2-local RMW.
__global__ void __launch_bounds__(256) hist8_kernel(
    const unsigned short* __restrict__ bin16, unsigned int* __restrict__ hist, int n)
{
    int owner = blockIdx.x & 7;
    int chunk = blockIdx.x >> 3;
    int base = chunk * (256 * KP) + threadIdx.x;
    int bn[KP], ok[KP];
#pragma unroll
    for (int k = 0; k < KP; ++k) {
        int p = base + k * 256;
        ok[k] = (p < n);
        bn[k] = bin16[ok[k] ? p : 0];
        ok[k] = ok[k] && ((bn[k] >> 12) == owner);
    }
#pragma unroll
    for (int k = 0; k < KP; ++k) {
        if (ok[k]) atomicAdd(&hist[bn[k]], 1u);
    }
}

__global__ void __launch_bounds__(SCAN_THREADS) scan_kernel(
    const unsigned int* __restrict__ hist, unsigned int* __restrict__ offs)
{
    __shared__ unsigned int partial[SCAN_THREADS];
    int t = threadIdx.x;
    unsigned int local[PER_THREAD];
    unsigned int s = 0;
    int base = t * PER_THREAD;
#pragma unroll
    for (int k = 0; k < PER_THREAD; ++k) {
        local[k] = s;
        s += hist[base + k];
    }
    partial[t] = s;
    __syncthreads();
    for (int d = 1; d < SCAN_THREADS; d <<= 1) {
        unsigned int v = (t >= d) ? partial[t - d] : 0u;
        __syncthreads();
        partial[t] += v;
        __syncthreads();
    }
    unsigned int chunk_excl = (t == 0) ? 0u : partial[t - 1];
#pragma unroll
    for (int k = 0; k < PER_THREAD; ++k)
        offs[base + k] = chunk_excl + local[k];
}

// Pass 2: octant-filtered scatter (atomics XCD-local; sorted-line writers all
// on one XCD -> partial stores merge in that L2). Payload: (pos, particle id).
__global__ void __launch_bounds__(256) scatter8_kernel(
    const float* __restrict__ pos, const unsigned short* __restrict__ bin16,
    float4* __restrict__ sorted, unsigned int* __restrict__ offs, int n)
{
    int owner = blockIdx.x & 7;
    int chunk = blockIdx.x >> 3;
    int base = chunk * (256 * KP) + threadIdx.x;
    int bn[KP], ok[KP];
#pragma unroll
    for (int k = 0; k < KP; ++k) {
        int p = base + k * 256;
        ok[k] = (p < n);
        bn[k] = bin16[ok[k] ? p : 0];
        ok[k] = ok[k] && ((bn[k] >> 12) == owner);
    }
    unsigned int off[KP];
#pragma unroll
    for (int k = 0; k < KP; ++k) {
        if (ok[k]) off[k] = atomicAdd(&offs[bn[k]], 1u);
    }
#pragma unroll
    for (int k = 0; k < KP; ++k) {
        if (ok[k]) {
            int p = base + k * 256;
            float4 v;
            v.x = pos[3 * p + 0];
            v.y = pos[3 * p + 1];
            v.z = pos[3 * p + 2];
            v.w = __int_as_float(p);
            sorted[off[k]] = v;
        }
    }
}

__global__ void __launch_bounds__(256) gather_kernel(
    const float* __restrict__ grid,
    const float4* __restrict__ sorted,
    float* __restrict__ out, int n)
{
    int j = blockIdx.x * blockDim.x + threadIdx.x;
    if (j >= n) return;

    float4 p = sorted[j];
    int idx = __float_as_int(p.w);

    float nx = p.x * INV_DX;
    float ny = p.y * INV_DX;
    float nz = p.z * INV_DX;

    int bx = (int)nx;
    int by = (int)ny;
    int bz = (int)nz;

    float lx = nx - (float)bx;
    float ly = ny - (float)by;
    float lz = nz - (float)bz;

    float wx[3], wy[3], wz[3];
    wx[0] = 0.5f * (1.0f - lx) * (1.0f - lx);
    wx[1] = 0.75f - (0.5f - lx) * (0.5f - lx);
    wx[2] = 0.5f * lx * lx;
    wy[0] = 0.5f * (1.0f - ly) * (1.0f - ly);
    wy[1] = 0.75f - (0.5f - ly) * (0.5f - ly);
    wy[2] = 0.5f * ly * ly;
    wz[0] = 0.5f * (1.0f - lz) * (1.0f - lz);
    wz[1] = 0.75f - (0.5f - lz) * (0.5f - lz);
    wz[2] = 0.5f * lz * lz;

    const int s1 = N_GRID * 3;
    const int s0 = N_GRID * N_GRID * 3;
    const float* gbase = grid + (long)bx * s0 + by * s1 + bz * 3;

    float ox = 0.0f, oy = 0.0f, oz = 0.0f;

#pragma unroll
    for (int a = 0; a < 3; ++a) {
#pragma unroll
        for (int b = 0; b < 3; ++b) {
            const float* pp = gbase + a * s0 + b * s1;
            float wab = wx[a] * wy[b];
            float g0x = pp[0], g0y = pp[1], g0z = pp[2];
            float g1x = pp[3], g1y = pp[4], g1z = pp[5];
            float g2x = pp[6], g2y = pp[7], g2z = pp[8];
            float w0 = wab * wz[0];
            float w1 = wab * wz[1];
            float w2 = wab * wz[2];
            ox += w0 * g0x + w1 * g1x + w2 * g2x;
            oy += w0 * g0y + w1 * g1y + w2 * g2y;
            oz += w0 * g0z + w1 * g1z + w2 * g2z;
        }
    }

    out[3 * idx + 0] = ox;
    out[3 * idx + 1] = oy;
    out[3 * idx + 2] = oz;
}

// Fallback: naive per-particle gather
__global__ void __launch_bounds__(256) g2p_naive_kernel(
    const float* __restrict__ grid, const float* __restrict__ pos,
    float* __restrict__ out, int n)
{
    int i = blockIdx.x * blockDim.x + threadIdx.x;
    if (i >= n) return;
    float px = pos[3 * i + 0], py = pos[3 * i + 1], pz = pos[3 * i + 2];
    float nx = px * INV_DX, ny = py * INV_DX, nz = pz * INV_DX;
    int bx = (int)nx, by = (int)ny, bz = (int)nz;
    float lx = nx - bx, ly = ny - by, lz = nz - bz;
    float wx[3], wy[3], wz[3];
    wx[0] = 0.5f * (1.0f - lx) * (1.0f - lx);
    wx[1] = 0.75f - (0.5f - lx) * (0.5f - lx);
    wx[2] = 0.5f * lx * lx;
    wy[0] = 0.5f * (1.0f - ly) * (1.0f - ly);
    wy[1] = 0.75f - (0.5f - ly) * (0.5f - ly);
    wy[2] = 0.5f * ly * ly;
    wz[0] = 0.5f * (1.0f - lz) * (1.0f - lz);
    wz[1] = 0.75f - (0.5f - lz) * (0.5f - lz);
    wz[2] = 0.5f * lz * lz;
    const int s1 = N_GRID * 3, s0 = N_GRID * N_GRID * 3;
    const float* gbase = grid + (long)bx * s0 + by * s1 + bz * 3;
    float ox = 0, oy = 0, oz = 0;
#pragma unroll
    for (int a = 0; a < 3; ++a)
#pragma unroll
        for (int b = 0; b < 3; ++b) {
            const float* pp = gbase + a * s0 + b * s1;
            float wab = wx[a] * wy[b];
            float w0 = wab * wz[0], w1 = wab * wz[1], w2 = wab * wz[2];
            ox += w0 * pp[0] + w1 * pp[3] + w2 * pp[6];
            oy += w0 * pp[1] + w1 * pp[4] + w2 * pp[7];
            oz += w0 * pp[2] + w1 * pp[5] + w2 * pp[8];
        }
    out[3 * i + 0] = ox;
    out[3 * i + 1] = oy;
    out[3 * i + 2] = oz;
}

extern "C" void kernel_launch(void* const* d_in, const int* in_sizes, int n_in,
                              void* d_out, int out_size, void* d_ws, size_t ws_size,
                              hipStream_t stream) {
    const float* grid = (const float*)d_in[0];
    const float* pos  = (const float*)d_in[1];
    float* out        = (float*)d_out;
    int n = in_sizes[1] / 3;

    int block = 256;
    int blocks = (n + block - 1) / block;
    int blocksK = (n + block * KP - 1) / (block * KP);

    // ws layout: [0,128K) hist | [128K,256K) offs | [256K, 256K+2n) bin16 |
    //            [align256, +16n) sorted
    size_t bin_off = 256u << 10;
    size_t sorted_off = (bin_off + (size_t)n * 2 + 255) & ~(size_t)255;
    size_t need = sorted_off + (size_t)n * sizeof(float4);

    if (ws_size < need) {
        g2p_naive_kernel<<<blocks, block, 0, stream>>>(grid, pos, out, n);
        return;
    }

    unsigned int* hist = (unsigned int*)d_ws;
    unsigned int* offs = hist + NBINS;
    unsigned short* bin16 = (unsigned short*)((char*)d_ws + bin_off);
    float4* sorted = (float4*)((char*)d_ws + sorted_off);

    hipMemsetAsync(hist, 0, NBINS * sizeof(unsigned int), stream);
    binify_kernel<<<blocksK, block, 0, stream>>>(pos, bin16, n);
    hist8_kernel<<<blocksK * 8, block, 0, stream>>>(bin16, hist, n);
    scan_kernel<<<1, SCAN_THREADS, 0, stream>>>(hist, offs);
    scatter8_kernel<<<blocksK * 8, block, 0, stream>>>(pos, bin16, sorted, offs, n);
    gather_kernel<<<blocks, block, 0, stream>>>(grid, sorted, out, n);
}

// Round 8
// 406.090 us; speedup vs baseline: 1.5240x; 1.1704x over previous
//
#include <hip/hip_runtime.h>

#define N_GRID 144
#define INV_DX 128.0f
#define NBINS 32768          // 32 x 32 x 32 bins of 4^3 cells
#define SCAN_THREADS 1024
#define PER_THREAD 32        // 1024 * 32 = 32768
#define KP 8                 // particles per thread in streaming passes

__device__ __forceinline__ int bin_of(float px, float py, float pz) {
    int bx = (int)(px * INV_DX);   // 0..127
    int by = (int)(py * INV_DX);
    int bz = (int)(pz * INV_DX);
    return ((bx >> 2) << 10) | ((by >> 2) << 5) | (bz >> 2);
}

// Pass 0: bin16[i] = bin index (coalesced read/write, no atomics)
__global__ void __launch_bounds__(256) binify_kernel(
    const float* __restrict__ pos, unsigned short* __restrict__ bin16, int n)
{
    int base = blockIdx.x * (blockDim.x * KP) + threadIdx.x;
#pragma unroll
    for (int k = 0; k < KP; ++k) {
        int p = base + k * 256;
        if (p < n) {
            float px = pos[3 * p + 0];
            float py = pos[3 * p + 1];
            float pz = pos[3 * p + 2];
            bin16[p] = (unsigned short)bin_of(px, py, pz);
        }
    }
}

// Pass 1: octant-filtered histogram (atomics land in an XCD-private 16KB
// hist slice under round-robin blockIdx->XCD mapping).
__global__ void __launch_bounds__(256) hist8_kernel(
    const unsigned short* __restrict__ bin16, unsigned int* __restrict__ hist, int n)
{
    int owner = blockIdx.x & 7;
    int chunk = blockIdx.x >> 3;
    int base = chunk * (256 * KP) + threadIdx.x;
    int bn[KP], ok[KP];
#pragma unroll
    for (int k = 0; k < KP; ++k) {
        int p = base + k * 256;
        ok[k] = (p < n);
        bn[k] = bin16[ok[k] ? p : 0];
        ok[k] = ok[k] && ((bn[k] >> 12) == owner);
    }
#pragma unroll
    for (int k = 0; k < KP; ++k) {
        if (ok[k]) atomicAdd(&hist[bn[k]], 1u);
    }
}

__global__ void __launch_bounds__(SCAN_THREADS) scan_kernel(
    const unsigned int* __restrict__ hist, unsigned int* __restrict__ offs)
{
    __shared__ unsigned int partial[SCAN_THREADS];
    int t = threadIdx.x;
    unsigned int local[PER_THREAD];
    unsigned int s = 0;
    int base = t * PER_THREAD;
#pragma unroll
    for (int k = 0; k < PER_THREAD; ++k) {
        local[k] = s;
        s += hist[base + k];
    }
    partial[t] = s;
    __syncthreads();
    for (int d = 1; d < SCAN_THREADS; d <<= 1) {
        unsigned int v = (t >= d) ? partial[t - d] : 0u;
        __syncthreads();
        partial[t] += v;
        __syncthreads();
    }
    unsigned int chunk_excl = (t == 0) ? 0u : partial[t - 1];
#pragma unroll
    for (int k = 0; k < PER_THREAD; ++k)
        offs[base + k] = chunk_excl + local[k];
}

// Pass 2: octant-filtered scatter; DENSE coalesced pos reads (all lanes),
// then filter. Atomics XCD-local; sorted-line writers all on one XCD.
__global__ void __launch_bounds__(256) scatter8_kernel(
    const float* __restrict__ pos, const unsigned short* __restrict__ bin16,
    float4* __restrict__ sorted, unsigned int* __restrict__ offs, int n)
{
    int owner = blockIdx.x & 7;
    int chunk = blockIdx.x >> 3;
    int base = chunk * (256 * KP) + threadIdx.x;
    float px[KP], py[KP], pz[KP];
    int bn[KP], ok[KP];
#pragma unroll
    for (int k = 0; k < KP; ++k) {
        int p = base + k * 256;
        ok[k] = (p < n);
        int q = ok[k] ? p : 0;
        px[k] = pos[3 * q + 0];
        py[k] = pos[3 * q + 1];
        pz[k] = pos[3 * q + 2];
        bn[k] = bin16[q];
        ok[k] = ok[k] && ((bn[k] >> 12) == owner);
    }
    unsigned int off[KP];
#pragma unroll
    for (int k = 0; k < KP; ++k) {
        if (ok[k]) off[k] = atomicAdd(&offs[bn[k]], 1u);
    }
#pragma unroll
    for (int k = 0; k < KP; ++k) {
        if (ok[k]) {
            int p = base + k * 256;
            float4 v;
            v.x = px[k]; v.y = py[k]; v.z = pz[k];
            v.w = __int_as_float(p);
            sorted[off[k]] = v;
        }
    }
}

// Pass 3: bin-centric gather. One 128-thread block per bin; stencil region
// (6x6x6 nodes x3 = 648 floats, 2.6KB) staged to LDS once; each particle's
// 27 grid reads become LDS reads. Bin blocks XCD-swizzled so each XCD
// re-reads only a 4.5MB x-slab of the grid (L2-fit).
__global__ void __launch_bounds__(128) gather_bin_kernel(
    const float* __restrict__ grid,
    const float4* __restrict__ sorted,
    const unsigned int* __restrict__ offs_end,
    const unsigned int* __restrict__ hist,
    float* __restrict__ out)
{
    // bijective XCD swizzle: 32768 = 8 * 4096
    int b = (blockIdx.x & 7) * 4096 + (blockIdx.x >> 3);

    unsigned int end = offs_end[b];
    unsigned int cnt = hist[b];
    if (cnt == 0) return;
    unsigned int start = end - cnt;

    int obx = 4 * (b >> 10);          // origin node x
    int oby = 4 * ((b >> 5) & 31);    // origin node y
    int obz = 4 * (b & 31);           // origin node z

    const int s1 = N_GRID * 3;
    const int s0 = N_GRID * N_GRID * 3;

    __shared__ float R[648];          // [6][6][18]: x,y rows of 18 z-floats
    const float* gorig = grid + (long)obx * s0 + oby * s1 + obz * 3;
    int tid = threadIdx.x;
#pragma unroll
    for (int f = tid; f < 648; f += 128) {
        int row = f / 18;             // 0..35  (x*6 + y)
        int zz = f - row * 18;
        R[f] = gorig[(row / 6) * s0 + (row % 6) * s1 + zz];
    }
    __syncthreads();

    for (unsigned int j = start + tid; j < end; j += 128) {
        float4 p = sorted[j];
        int idx = __float_as_int(p.w);

        float nx = p.x * INV_DX;
        float ny = p.y * INV_DX;
        float nz = p.z * INV_DX;
        int bx = (int)nx;
        int by = (int)ny;
        int bz = (int)nz;
        float lx = nx - (float)bx;
        float ly = ny - (float)by;
        float lz = nz - (float)bz;

        float wx[3], wy[3], wz[3];
        wx[0] = 0.5f * (1.0f - lx) * (1.0f - lx);
        wx[1] = 0.75f - (0.5f - lx) * (0.5f - lx);
        wx[2] = 0.5f * lx * lx;
        wy[0] = 0.5f * (1.0f - ly) * (1.0f - ly);
        wy[1] = 0.75f - (0.5f - ly) * (0.5f - ly);
        wy[2] = 0.5f * ly * ly;
        wz[0] = 0.5f * (1.0f - lz) * (1.0f - lz);
        wz[1] = 0.75f - (0.5f - lz) * (0.5f - lz);
        wz[2] = 0.5f * lz * lz;

        int rx = bx - obx;            // 0..3
        int ry = by - oby;
        int rz = bz - obz;

        float ox = 0.0f, oy = 0.0f, oz = 0.0f;
#pragma unroll
        for (int a = 0; a < 3; ++a) {
#pragma unroll
            for (int bb = 0; bb < 3; ++bb) {
                const float* pp = &R[((rx + a) * 6 + (ry + bb)) * 18 + rz * 3];
                float wab = wx[a] * wy[bb];
                float w0 = wab * wz[0];
                float w1 = wab * wz[1];
                float w2 = wab * wz[2];
                ox += w0 * pp[0] + w1 * pp[3] + w2 * pp[6];
                oy += w0 * pp[1] + w1 * pp[4] + w2 * pp[7];
                oz += w0 * pp[2] + w1 * pp[5] + w2 * pp[8];
            }
        }

        out[3 * idx + 0] = ox;
        out[3 * idx + 1] = oy;
        out[3 * idx + 2] = oz;
    }
}

// Fallback: naive per-particle gather
__global__ void __launch_bounds__(256) g2p_naive_kernel(
    const float* __restrict__ grid, const float* __restrict__ pos,
    float* __restrict__ out, int n)
{
    int i = blockIdx.x * blockDim.x + threadIdx.x;
    if (i >= n) return;
    float px = pos[3 * i + 0], py = pos[3 * i + 1], pz = pos[3 * i + 2];
    float nx = px * INV_DX, ny = py * INV_DX, nz = pz * INV_DX;
    int bx = (int)nx, by = (int)ny, bz = (int)nz;
    float lx = nx - bx, ly = ny - by, lz = nz - bz;
    float wx[3], wy[3], wz[3];
    wx[0] = 0.5f * (1.0f - lx) * (1.0f - lx);
    wx[1] = 0.75f - (0.5f - lx) * (0.5f - lx);
    wx[2] = 0.5f * lx * lx;
    wy[0] = 0.5f * (1.0f - ly) * (1.0f - ly);
    wy[1] = 0.75f - (0.5f - ly) * (0.5f - ly);
    wy[2] = 0.5f * ly * ly;
    wz[0] = 0.5f * (1.0f - lz) * (1.0f - lz);
    wz[1] = 0.75f - (0.5f - lz) * (0.5f - lz);
    wz[2] = 0.5f * lz * lz;
    const int s1 = N_GRID * 3, s0 = N_GRID * N_GRID * 3;
    const float* gbase = grid + (long)bx * s0 + by * s1 + bz * 3;
    float ox = 0, oy = 0, oz = 0;
#pragma unroll
    for (int a = 0; a < 3; ++a)
#pragma unroll
        for (int b = 0; b < 3; ++b) {
            const float* pp = gbase + a * s0 + b * s1;
            float wab = wx[a] * wy[b];
            float w0 = wab * wz[0], w1 = wab * wz[1], w2 = wab * wz[2];
            ox += w0 * pp[0] + w1 * pp[3] + w2 * pp[6];
            oy += w0 * pp[1] + w1 * pp[4] + w2 * pp[7];
            oz += w0 * pp[2] + w1 * pp[5] + w2 * pp[8];
        }
    out[3 * i + 0] = ox;
    out[3 * i + 1] = oy;
    out[3 * i + 2] = oz;
}

extern "C" void kernel_launch(void* const* d_in, const int* in_sizes, int n_in,
                              void* d_out, int out_size, void* d_ws, size_t ws_size,
                              hipStream_t stream) {
    const float* grid = (const float*)d_in[0];
    const float* pos  = (const float*)d_in[1];
    float* out        = (float*)d_out;
    int n = in_sizes[1] / 3;

    int block = 256;
    int blocks = (n + block - 1) / block;
    int blocksK = (n + block * KP - 1) / (block * KP);

    // ws layout: [0,128K) hist | [128K,256K) offs | [256K, 256K+2n) bin16 |
    //            [align256, +16n) sorted
    size_t bin_off = 256u << 10;
    size_t sorted_off = (bin_off + (size_t)n * 2 + 255) & ~(size_t)255;
    size_t need = sorted_off + (size_t)n * sizeof(float4);

    if (ws_size < need) {
        g2p_naive_kernel<<<blocks, block, 0, stream>>>(grid, pos, out, n);
        return;
    }

    unsigned int* hist = (unsigned int*)d_ws;
    unsigned int* offs = hist + NBINS;
    unsigned short* bin16 = (unsigned short*)((char*)d_ws + bin_off);
    float4* sorted = (float4*)((char*)d_ws + sorted_off);

    hipMemsetAsync(hist, 0, NBINS * sizeof(unsigned int), stream);
    binify_kernel<<<blocksK, block, 0, stream>>>(pos, bin16, n);
    hist8_kernel<<<blocksK * 8, block, 0, stream>>>(bin16, hist, n);
    scan_kernel<<<1, SCAN_THREADS, 0, stream>>>(hist, offs);
    scatter8_kernel<<<blocksK * 8, block, 0, stream>>>(pos, bin16, sorted, offs, n);
    gather_bin_kernel<<<NBINS, 128, 0, stream>>>(grid, sorted, offs, hist, out);
}